// Round 4
// baseline (3474.407 us; speedup 1.0000x reference)
//
#include <hip/hip_runtime.h>

// Sizes (fixed by the problem)
#define DZc 512
#define Bc  64
#define Tc  1000
#define DUc 16
#define DXc 256

#define KTOT 17            // 16 W k-tiles + 1 augmented (Wu, v hi/lo) tile
#define NFRAG (KTOT * 8)   // 136 fragments per wave (8 n-tiles each, 4 waves)
#define NREG  108          // frags in VGPR/AGPR per wave (432 regs)
#define NLDS  (NFRAG - NREG) // 28 frags per wave in LDS (112 KB total)
#define AROW  552          // padded activation row length (bf16 elems)

// Workspace layout:
//   Wp : bf16 augmented W' [544 k][512 n] in B-fragment order  278528 ushort
//   Bp : bf16 B_obs in B-fragment order                        131072 ushort
//   zs : bf16 z-history [T][B][DZ]                             32768000 ushort

typedef __attribute__((ext_vector_type(4))) float f32x4;
typedef __attribute__((ext_vector_type(8))) short s16x8;

__device__ __forceinline__ unsigned short f2bf(float x) {
  unsigned u = __builtin_bit_cast(unsigned, x);
  u = u + 0x7FFFu + ((u >> 16) & 1u);   // round-to-nearest-even
  return (unsigned short)(u >> 16);
}
__device__ __forceinline__ float bf2f(unsigned short u) {
  unsigned x = ((unsigned)u) << 16;
  return __builtin_bit_cast(float, x);
}

// Pack augmented W' into bf16 MFMA B-fragments.
// W'[n][k]: k<512 -> W[n][k]; k in [512,544) -> Wu[n][k&15].
// Fragment (kt,nt): lane l elem j holds B[k][n], n = nt*16+(l&15),
// k = kt*32+(l>>4)*8+j.  Linear: Wp[((kt*32+nt)*64+l)*8+j]
__global__ void pack_w_kernel(const float* __restrict__ W,
                              const float* __restrict__ Wu,
                              unsigned short* __restrict__ Wp) {
  int d = blockIdx.x * 256 + threadIdx.x;          // 278528 total
  int j = d & 7, l = (d >> 3) & 63, nt = (d >> 9) & 31, kt = d >> 14;
  int n = nt * 16 + (l & 15);
  int k = kt * 32 + ((l >> 4) << 3) + j;
  float val = (k < DZc) ? W[n * DZc + k] : Wu[n * DUc + (k & 15)];
  Wp[d] = f2bf(val);
}

// Pack B_obs[512][256] ([z][x]) into bf16 B-fragments: B[k][n] = B_obs[k][n].
__global__ void pack_b_kernel(const float* __restrict__ B,
                              unsigned short* __restrict__ Bp) {
  int d = blockIdx.x * 256 + threadIdx.x;          // 131072 total
  int j = d & 7, l = (d >> 3) & 63, nt = (d >> 9) & 15, kt = d >> 13;
  int n = nt * 16 + (l & 15);
  int k = kt * 32 + ((l >> 4) << 3) + j;
  Bp[d] = f2bf(B[k * DXc + n]);
}

// Recurrence: 4 WGs x 256 threads (4 waves at 1 wave/SIMD -> 512 VGPR/wave),
// 16 trials each. Each wave owns 8 n-tiles (128 outputs): 108 W-frags in
// registers + 28 in LDS. z state lives in the MFMA accumulators. One
// lgkmcnt-only barrier per step; double-buffered activation LDS.
__global__ __launch_bounds__(256, 1) void rnn_rec_kernel(
    const float* __restrict__ z0, const float* __restrict__ v,
    const float* __restrict__ h, const float* __restrict__ dp,
    const unsigned short* __restrict__ Wp, unsigned short* __restrict__ zs) {
  __shared__ unsigned short wlds[4][NLDS][512];    // 112 KiB
  __shared__ unsigned short abuf[2][16][AROW];     // 34.5 KiB (double-buffered)

  const int tid = threadIdx.x;
  const int lane = tid & 63;
  const int w = tid >> 6;                          // wave 0..3
  const int l15 = lane & 15;
  const int lg = lane >> 4;
  const int b0 = blockIdx.x * 16;

  // ---- one-time: W fragments into regs (c<NREG) + LDS ----
  s16x8 wr[NREG];
#pragma unroll
  for (int c = 0; c < NFRAG; ++c) {
    int kt = c >> 3, nt = c & 7;                   // nt within wave
    int ntg = w * 8 + nt;                          // global n-tile
    s16x8 f = *(const s16x8*)(Wp + ((size_t)((kt * 32 + ntg) * 64 + lane)) * 8);
    if (c < NREG) wr[c] = f;
    else *(s16x8*)&wlds[w][c - NREG][lane * 8] = f;
  }

  // ---- one-time: z0 into acc, h into regs ----
  float hreg[8];
  f32x4 acc[8];
#pragma unroll
  for (int nt = 0; nt < 8; ++nt) {
    hreg[nt] = h[w * 128 + nt * 16 + l15];
#pragma unroll
    for (int r = 0; r < 4; ++r)
      acc[nt][r] = z0[(size_t)(b0 + lg * 4 + r) * DZc + w * 128 + nt * 16 + l15];
  }
  const float decay = expf(-expf(dp[0]));

  // v staging: all 256 threads own one (trial, du) slot
  const int du = tid & 15, trr = tid >> 4;
  const size_t vbase = ((size_t)(b0 + trr) * DUc + du) * Tc;
  float vcur = v[vbase];

  // initial activation + v0 into abuf[0]
#pragma unroll
  for (int nt = 0; nt < 8; ++nt)
#pragma unroll
    for (int r = 0; r < 4; ++r) {
      float av = acc[nt][r] - hreg[nt];
      abuf[0][lg * 4 + r][w * 128 + nt * 16 + l15] = f2bf(av > 0.f ? av : 0.f);
    }
  {
    unsigned short hi = f2bf(vcur);
    abuf[0][trr][512 + du] = hi;
    abuf[0][trr][528 + du] = f2bf(vcur - bf2f(hi));
  }

  // zs [t][b][dz]: base for (t=0, r=0, nt=0)
  unsigned short* zbase = zs + (size_t)(b0 + lg * 4) * DZc + w * 128 + l15;

  int p = 0;
  for (int t = 0; t < Tc; ++t) {
    // lgkmcnt-only barrier: LDS writes visible, global ops stay in flight
    asm volatile("s_waitcnt lgkmcnt(0)\n\ts_barrier" ::: "memory");

    // prefetch next step's v
    float vnext = v[vbase + (t + 1 < Tc ? t + 1 : Tc - 1)];

#pragma unroll
    for (int nt = 0; nt < 8; ++nt)
#pragma unroll
      for (int r = 0; r < 4; ++r) acc[nt][r] *= decay;

#pragma unroll
    for (int kt = 0; kt < KTOT; ++kt) {
      s16x8 af = *(const s16x8*)&abuf[p][l15][kt * 32 + lg * 8];
#pragma unroll
      for (int nt = 0; nt < 8; ++nt) {
        int c = kt * 8 + nt;
        s16x8 bf = (c < NREG) ? wr[c]
                              : *(const s16x8*)&wlds[w][c - NREG][lane * 8];
        acc[nt] = __builtin_amdgcn_mfma_f32_16x16x32_bf16(af, bf, acc[nt], 0, 0, 0);
      }
    }

    // store z_{t+1} to zs[t][b][dz] (fire-and-forget, crosses the barrier)
#pragma unroll
    for (int nt = 0; nt < 8; ++nt)
#pragma unroll
      for (int r = 0; r < 4; ++r)
        zbase[r * DZc + nt * 16] = f2bf(acc[nt][r]);
    zbase += Bc * DZc;

    // write phase: a(t+1) + v(t+1) into the other buffer (safe: all waves
    // finished reading buf p^1 before this step's barrier)
#pragma unroll
    for (int nt = 0; nt < 8; ++nt)
#pragma unroll
      for (int r = 0; r < 4; ++r) {
        float av = acc[nt][r] - hreg[nt];
        abuf[p ^ 1][lg * 4 + r][w * 128 + nt * 16 + l15] = f2bf(av > 0.f ? av : 0.f);
      }
    {
      unsigned short hi = f2bf(vnext);
      abuf[p ^ 1][trr][512 + du] = hi;
      abuf[p ^ 1][trr][528 + du] = f2bf(vnext - bf2f(hi));
    }
    p ^= 1;
    vcur = vnext;
  }
}

// Projection: x[b][xo][t] = sum_z B_obs[z][xo] * zs[t][b][z] + Bias[xo].
// One WG (256 thr = 4 waves) per (b, 16-t tile); 63 tiles (last masked).
__global__ __launch_bounds__(256, 1) void rnn_proj_kernel(
    const unsigned short* __restrict__ zs, const unsigned short* __restrict__ Bp,
    const float* __restrict__ Bias, float* __restrict__ x) {
  const int wg = blockIdx.x;                       // 64*63 = 4032
  const int b = wg / 63;
  const int tbase = (wg % 63) * 16;
  const int tid = threadIdx.x;
  const int lane = tid & 63;
  const int w = tid >> 6;
  const int l15 = lane & 15, lg = lane >> 4;

  const int trow = tbase + l15;
  const int trc = trow < Tc ? trow : Tc - 1;
  const unsigned short* abase = zs + ((size_t)trc * Bc + b) * DZc + lg * 8;
  const s16x8 zz = {0, 0, 0, 0, 0, 0, 0, 0};

  f32x4 acc[4];
#pragma unroll
  for (int n = 0; n < 4; ++n)
#pragma unroll
    for (int e = 0; e < 4; ++e) acc[n][e] = 0.f;

#pragma unroll
  for (int kt = 0; kt < 16; ++kt) {
    s16x8 af = *(const s16x8*)(abase + kt * 32);
    af = (trow < Tc) ? af : zz;                    // mask pad t-rows
#pragma unroll
    for (int n = 0; n < 4; ++n) {
      s16x8 bf = *(const s16x8*)(Bp + (size_t)((kt * 16 + w * 4 + n) * 64 + lane) * 8);
      acc[n] = __builtin_amdgcn_mfma_f32_16x16x32_bf16(af, bf, acc[n], 0, 0, 0);
    }
  }

  const int t = tbase + lg * 4;                    // regs cover t..t+3
  if (t < Tc) {
#pragma unroll
    for (int n = 0; n < 4; ++n) {
      int xo = (w * 4 + n) * 16 + l15;
      float bias = Bias[xo];
      f32x4 val = acc[n];
#pragma unroll
      for (int e = 0; e < 4; ++e) val[e] += bias;
      *(f32x4*)(x + ((size_t)b * DXc + xo) * Tc + t) = val;
    }
  }
}

extern "C" void kernel_launch(void* const* d_in, const int* in_sizes, int n_in,
                              void* d_out, int out_size, void* d_ws, size_t ws_size,
                              hipStream_t stream) {
  const float* z0   = (const float*)d_in[0];
  const float* v    = (const float*)d_in[1];
  const float* W    = (const float*)d_in[2];
  const float* Wu   = (const float*)d_in[3];
  const float* h    = (const float*)d_in[4];
  const float* dp   = (const float*)d_in[5];
  const float* Bo   = (const float*)d_in[6];
  const float* Bias = (const float*)d_in[7];
  float* x = (float*)d_out;

  unsigned short* Wp = (unsigned short*)d_ws;          // 278528 ushort
  unsigned short* Bp = Wp + 278528;                    // 131072 ushort
  unsigned short* zs = Bp + 131072;                    // 1000*64*512 ushort

  pack_w_kernel<<<1088, 256, 0, stream>>>(W, Wu, Wp);
  pack_b_kernel<<<512, 256, 0, stream>>>(Bo, Bp);
  rnn_rec_kernel<<<4, 256, 0, stream>>>(z0, v, h, dp, Wp, zs);
  rnn_proj_kernel<<<4032, 256, 0, stream>>>(zs, Bp, Bias, x);
}

// Round 6
// 2009.331 us; speedup vs baseline: 1.7291x; 1.7291x over previous
//
#include <hip/hip_runtime.h>

// Sizes (fixed by the problem)
#define DZc 512
#define Bc  64
#define Tc  1000
#define DUc 16
#define DXc 256
#define AROW 552           // padded activation row length (bf16 elems)

// Workspace layout:
//   Wp   : bf16 augmented W' [544 k][512 n] B-fragment order  278528 ushort
//   Bp   : bf16 B_obs in B-fragment order                     131072 ushort
//   zs   : bf16 z-history [T][B][DZ]                          32768000 ushort
//   flags: 8 x u32 pair-exchange flags (memset 0 each call)

typedef __attribute__((ext_vector_type(4))) float f32x4;
typedef __attribute__((ext_vector_type(8))) short s16x8;
typedef __attribute__((ext_vector_type(4))) unsigned u32x4;

__device__ __forceinline__ unsigned short f2bf(float x) {
  unsigned u = __builtin_bit_cast(unsigned, x);
  u = u + 0x7FFFu + ((u >> 16) & 1u);   // round-to-nearest-even
  return (unsigned short)(u >> 16);
}
__device__ __forceinline__ float bf2f(unsigned short u) {
  unsigned x = ((unsigned)u) << 16;
  return __builtin_bit_cast(float, x);
}
// Pack (n, n+1) bf16 pair into a u32 (valid on EVEN lanes) via DPP lane swap.
__device__ __forceinline__ unsigned pack_pair(float val) {
  unsigned bf = f2bf(val);
  unsigned sw = (unsigned)__builtin_amdgcn_mov_dpp((int)bf, 0xB1, 0xF, 0xF, true);
  return bf | (sw << 16);   // even lane: low = self(n), high = neighbor(n+1)
}

// Pack augmented W' into bf16 MFMA B-fragments.
// W'[n][k]: k<512 -> W[n][k]; k in [512,544) -> Wu[n][k&15].
// Fragment (kt,nt): lane l elem j holds B[k][n], n = nt*16+(l&15),
// k = kt*32+(l>>4)*8+j.  Linear: Wp[((kt*32+nt)*64+l)*8+j]
__global__ void pack_w_kernel(const float* __restrict__ W,
                              const float* __restrict__ Wu,
                              unsigned short* __restrict__ Wp) {
  int d = blockIdx.x * 256 + threadIdx.x;          // 278528 total
  int j = d & 7, l = (d >> 3) & 63, nt = (d >> 9) & 31, kt = d >> 14;
  int n = nt * 16 + (l & 15);
  int k = kt * 32 + ((l >> 4) << 3) + j;
  float val = (k < DZc) ? W[n * DZc + k] : Wu[n * DUc + (k & 15)];
  Wp[d] = f2bf(val);
}

// Pack B_obs[512][256] ([z][x]) into bf16 B-fragments: B[k][n] = B_obs[k][n].
__global__ void pack_b_kernel(const float* __restrict__ B,
                              unsigned short* __restrict__ Bp) {
  int d = blockIdx.x * 256 + threadIdx.x;          // 131072 total
  int j = d & 7, l = (d >> 3) & 63, nt = (d >> 9) & 15, kt = d >> 13;
  int n = nt * 16 + (l & 15);
  int k = kt * 32 + ((l >> 4) << 3) + j;
  Bp[d] = f2bf(B[k * DXc + n]);
}

// Recurrence with N-split pairs: 8 active WGs = 4 trial-groups x 2 n-halves.
// Each WG: 8 waves x 64, 16 trials, 256 outputs; 34 W-frags/wave = 136 VGPRs
// -> ALL W in registers, zero W LDS traffic. z-halves exchanged through zs
// via relaxed agent-scope u32 atomic stores (write-through coherent) + a
// per-pair flag published AFTER each iteration completes (deadlock-free).
__global__ __launch_bounds__(512, 2) void rnn_rec_kernel(
    const float* __restrict__ z0, const float* __restrict__ v,
    const float* __restrict__ h, const float* __restrict__ dp,
    const unsigned short* __restrict__ Wp, unsigned short* __restrict__ zs,
    unsigned int* __restrict__ flags) {
  __shared__ __align__(16) unsigned short abuf[2][16][AROW];   // 34.5 KiB

  const int bid = blockIdx.x;
  const int g = bid & 7;                           // trial group candidate
  const int s = bid >> 3;                          // n-half
  if (g >= 4) return;                              // 8 idle blocks exit
  const int tid = threadIdx.x;
  const int lane = tid & 63;
  const int w = tid >> 6;                          // wave 0..7
  const int l15 = lane & 15;
  const int lg = lane >> 4;
  const int b0 = g * 16;
  const int nbase = s * 256 + w * 32;              // wave's first output
  const int s8 = s * 8, o8 = 8 - s8;               // own / other kt bases

  // ---- one-time: 34 W fragments into regs, own-kt-first ordering ----
  // c = i*2 + ntl ; i: 0..7 own kts (s8+i), 8 = v tile (16), 9..16 partner
  s16x8 wr[34];
#pragma unroll
  for (int i = 0; i < 17; ++i) {
    int kt = (i < 8) ? (s8 + i) : (i == 8) ? 16 : (o8 + (i - 9));
#pragma unroll
    for (int ntl = 0; ntl < 2; ++ntl) {
      int nt = s * 16 + w * 2 + ntl;
      wr[i * 2 + ntl] =
          *(const s16x8*)(Wp + ((size_t)((kt * 32 + nt) * 64 + lane)) * 8);
    }
  }

  // ---- one-time: z0 into acc, h into regs ----
  float hreg[2];
  f32x4 acc[2];
#pragma unroll
  for (int ntl = 0; ntl < 2; ++ntl) {
    hreg[ntl] = h[nbase + ntl * 16 + l15];
#pragma unroll
    for (int r = 0; r < 4; ++r)
      acc[ntl][r] = z0[(size_t)(b0 + lg * 4 + r) * DZc + nbase + ntl * 16 + l15];
  }
  const float decay = expf(-expf(dp[0]));

  // partner-insert slot: thread -> (trial, 8-k chunk of partner half)
  const int ptrial = tid >> 5;                     // 0..15
  const int koff = (tid & 31) * 8;                 // 0..248
  const int pk = (1 - s) * 256 + koff;             // partner k base
  float hpart[8];
#pragma unroll
  for (int j = 0; j < 8; ++j) hpart[j] = h[pk + j];

  // v staging: threads 0..255 own one (trial, du) slot
  const int du = tid & 15, trr = tid >> 4;
  const size_t vbase = ((size_t)(b0 + trr) * DUc + du) * Tc;
  float vcur = (tid < 256) ? v[vbase] : 0.f;

  // ---- prologue: build FULL a(0) from z0 (f32) + v(0) ----
#pragma unroll
  for (int half = 0; half < 2; ++half) {
    int kk = half * 256 + koff;
    const float* zp = z0 + (size_t)(b0 + ptrial) * DZc + kk;
    s16x8 ov;
#pragma unroll
    for (int j = 0; j < 8; ++j) {
      float av = zp[j] - h[kk + j];
      ov[j] = (short)f2bf(av > 0.f ? av : 0.f);
    }
    *(s16x8*)&abuf[0][ptrial][kk] = ov;
  }
  if (tid < 256) {
    unsigned short hi = f2bf(vcur);
    abuf[0][trr][512 + du] = hi;
    abuf[0][trr][528 + du] = f2bf(vcur - bf2f(hi));
  }

  unsigned int* myflag = flags + (g * 2 + s);
  unsigned int* pflag = flags + (g * 2 + (s ^ 1));
  unsigned* zs32 = (unsigned*)zs;                  // zs as packed u32 words

  int p = 0;
  for (int t = 0; t < Tc; ++t) {
    // ---- phase 1: wait partner z_t visible, load it (ordinary dwordx4:
    // address is fresh every t, never cached on this XCD) ----
    u32x4 pz4 = {0, 0, 0, 0};
    if (t > 0) {
      int iters = 0;
      while (__hip_atomic_load(pflag, __ATOMIC_RELAXED,
                               __HIP_MEMORY_SCOPE_AGENT) < (unsigned)t) {
        __builtin_amdgcn_s_sleep(2);
        if (++iters > (1 << 22)) break;            // failsafe: no hangs
      }
      asm volatile("" ::: "memory");               // no hoisting past spin
      pz4 = *(const u32x4*)(zs32 +
            ((size_t)(t - 1) * Bc + b0 + ptrial) * 256 + (pk >> 1));
    }
    float vnext = (tid < 256) ? v[vbase + (t + 1 < Tc ? t + 1 : Tc - 1)] : 0.f;
#pragma unroll
    for (int ntl = 0; ntl < 2; ++ntl)
#pragma unroll
      for (int r = 0; r < 4; ++r) acc[ntl][r] *= decay;

    // (A) own a(t) + v(t) writes (tail of t-1 / prologue) visible
    asm volatile("s_waitcnt lgkmcnt(0)\n\ts_barrier" ::: "memory");

    // ---- phase 2: MFMA own 8 kts + v tile ----
#pragma unroll
    for (int i = 0; i < 9; ++i) {
      int kt = (i < 8) ? (s8 + i) : 16;
      s16x8 af = *(const s16x8*)&abuf[p][l15][kt * 32 + lg * 8];
      acc[0] = __builtin_amdgcn_mfma_f32_16x16x32_bf16(af, wr[i * 2 + 0], acc[0], 0, 0, 0);
      acc[1] = __builtin_amdgcn_mfma_f32_16x16x32_bf16(af, wr[i * 2 + 1], acc[1], 0, 0, 0);
    }

    // ---- phase 3: insert partner activations (one b128 per thread) ----
    if (t > 0) {
      s16x8 ov;
#pragma unroll
      for (int j2 = 0; j2 < 4; ++j2) {
        unsigned wd = pz4[j2];
        float alo = bf2f((unsigned short)(wd & 0xFFFFu)) - hpart[j2 * 2];
        float ahi = bf2f((unsigned short)(wd >> 16)) - hpart[j2 * 2 + 1];
        ov[j2 * 2] = (short)f2bf(alo > 0.f ? alo : 0.f);
        ov[j2 * 2 + 1] = (short)f2bf(ahi > 0.f ? ahi : 0.f);
      }
      *(s16x8*)&abuf[p][ptrial][pk] = ov;
    }
    asm volatile("s_waitcnt lgkmcnt(0)\n\ts_barrier" ::: "memory");  // (B)

    // ---- phase 4: MFMA partner 8 kts ----
#pragma unroll
    for (int i = 0; i < 8; ++i) {
      int kt = o8 + i;
      s16x8 af = *(const s16x8*)&abuf[p][l15][kt * 32 + lg * 8];
      acc[0] = __builtin_amdgcn_mfma_f32_16x16x32_bf16(af, wr[18 + i * 2], acc[0], 0, 0, 0);
      acc[1] = __builtin_amdgcn_mfma_f32_16x16x32_bf16(af, wr[19 + i * 2], acc[1], 0, 0, 0);
    }

    // ---- phase 5: z_{t+1} own half -> zs[t] as packed u32 agent-scope
    // atomic stores (write-through coherent; even lanes only) ----
    const size_t zrow0 = (size_t)t * Bc + b0 + lg * 4;
#pragma unroll
    for (int ntl = 0; ntl < 2; ++ntl)
#pragma unroll
      for (int r = 0; r < 4; ++r) {
        unsigned wdz = pack_pair(acc[ntl][r]);
        if (!(lane & 1))
          __hip_atomic_store(
              zs32 + (zrow0 + r) * 256 + (nbase >> 1) + ntl * 8 + (l15 >> 1),
              wdz, __ATOMIC_RELAXED, __HIP_MEMORY_SCOPE_AGENT);
      }

    // ---- phase 6: own a(t+1) packed b32 LDS writes + v(t+1) ----
#pragma unroll
    for (int ntl = 0; ntl < 2; ++ntl)
#pragma unroll
      for (int r = 0; r < 4; ++r) {
        float av = acc[ntl][r] - hreg[ntl];
        unsigned wda = pack_pair(av > 0.f ? av : 0.f);
        if (!(lane & 1))
          *(unsigned*)&abuf[p ^ 1][lg * 4 + r][nbase + ntl * 16 + (l15 & ~1)] = wda;
      }
    if (tid < 256) {
      unsigned short hi = f2bf(vnext);
      abuf[p ^ 1][trr][512 + du] = hi;
      abuf[p ^ 1][trr][528 + du] = f2bf(vnext - bf2f(hi));
    }

    // ---- phase 7: drain z stores (per wave), sync, publish flag ----
    asm volatile("s_waitcnt vmcnt(0)" ::: "memory");
    __builtin_amdgcn_s_barrier();
    if (tid == 0)
      __hip_atomic_store(myflag, (unsigned)(t + 1), __ATOMIC_RELAXED,
                         __HIP_MEMORY_SCOPE_AGENT);
    p ^= 1;
    vcur = vnext;
  }
}

// Projection: x[b][xo][t] = sum_z B_obs[z][xo] * zs[t][b][z] + Bias[xo].
// One WG (256 thr = 4 waves) per (b, 16-t tile); 63 tiles (last masked).
__global__ __launch_bounds__(256, 1) void rnn_proj_kernel(
    const unsigned short* __restrict__ zs, const unsigned short* __restrict__ Bp,
    const float* __restrict__ Bias, float* __restrict__ x) {
  const int wg = blockIdx.x;                       // 64*63 = 4032
  const int b = wg / 63;
  const int tbase = (wg % 63) * 16;
  const int tid = threadIdx.x;
  const int lane = tid & 63;
  const int w = tid >> 6;
  const int l15 = lane & 15, lg = lane >> 4;

  const int trow = tbase + l15;
  const int trc = trow < Tc ? trow : Tc - 1;
  const unsigned short* abase = zs + ((size_t)trc * Bc + b) * DZc + lg * 8;
  const s16x8 zz = {0, 0, 0, 0, 0, 0, 0, 0};

  f32x4 acc[4];
#pragma unroll
  for (int n = 0; n < 4; ++n)
#pragma unroll
    for (int e = 0; e < 4; ++e) acc[n][e] = 0.f;

#pragma unroll
  for (int kt = 0; kt < 16; ++kt) {
    s16x8 af = *(const s16x8*)(abase + kt * 32);
    af = (trow < Tc) ? af : zz;                    // mask pad t-rows
#pragma unroll
    for (int n = 0; n < 4; ++n) {
      s16x8 bf = *(const s16x8*)(Bp + (size_t)((kt * 16 + w * 4 + n) * 64 + lane) * 8);
      acc[n] = __builtin_amdgcn_mfma_f32_16x16x32_bf16(af, bf, acc[n], 0, 0, 0);
    }
  }

  const int t = tbase + lg * 4;                    // regs cover t..t+3
  if (t < Tc) {
#pragma unroll
    for (int n = 0; n < 4; ++n) {
      int xo = (w * 4 + n) * 16 + l15;
      float bias = Bias[xo];
      f32x4 val = acc[n];
#pragma unroll
      for (int e = 0; e < 4; ++e) val[e] += bias;
      *(f32x4*)(x + ((size_t)b * DXc + xo) * Tc + t) = val;
    }
  }
}

extern "C" void kernel_launch(void* const* d_in, const int* in_sizes, int n_in,
                              void* d_out, int out_size, void* d_ws, size_t ws_size,
                              hipStream_t stream) {
  const float* z0   = (const float*)d_in[0];
  const float* v    = (const float*)d_in[1];
  const float* W    = (const float*)d_in[2];
  const float* Wu   = (const float*)d_in[3];
  const float* h    = (const float*)d_in[4];
  const float* dp   = (const float*)d_in[5];
  const float* Bo   = (const float*)d_in[6];
  const float* Bias = (const float*)d_in[7];
  float* x = (float*)d_out;

  unsigned short* Wp = (unsigned short*)d_ws;          // 278528 ushort
  unsigned short* Bp = Wp + 278528;                    // 131072 ushort
  unsigned short* zs = Bp + 131072;                    // 1000*64*512 ushort
  unsigned int* flags = (unsigned int*)(zs + 32768000);

  hipMemsetAsync(flags, 0, 8 * sizeof(unsigned int), stream);
  pack_w_kernel<<<1088, 256, 0, stream>>>(W, Wu, Wp);
  pack_b_kernel<<<512, 256, 0, stream>>>(Bo, Bp);
  rnn_rec_kernel<<<16, 512, 0, stream>>>(z0, v, h, dp, Wp, zs, flags);
  rnn_proj_kernel<<<4032, 256, 0, stream>>>(zs, Bp, Bias, x);
}